// Round 2
// baseline (300.702 us; speedup 1.0000x reference)
//
#include <hip/hip_runtime.h>
#include <hip/hip_bf16.h>
#include <math.h>

// ---------------------------------------------------------------------------
// Problem shapes
// ---------------------------------------------------------------------------
#define NN 400000
#define HH 256
#define GG 1024
#define E1 7
#define E2 70
#define E3 300

// Output layout (flat f32):
#define OFF_L1 0
#define OFF_L2 7168
#define OFF_L3 78848
#define OFF_P1 386048
#define OFF_G  393216

// ---------------------------------------------------------------------------
// Kernel 1: segment mean.  One block (256 thr = 4 waves) per graph.
// (unchanged from R0 for A/B attribution)
// ---------------------------------------------------------------------------
__global__ __launch_bounds__(256) void seg_mean_kernel(
    const float* __restrict__ emb, const int* __restrict__ bidx,
    float* __restrict__ gf) {
  const int g = blockIdx.x;
  const int tid = threadIdx.x;
  __shared__ int seg[2];
  if (tid < 2) {
    const int target = g + tid;  // lower_bound(target)
    int lo = 0, hi = NN;
    while (lo < hi) {
      int mid = (lo + hi) >> 1;
      if (bidx[mid] < target) lo = mid + 1; else hi = mid;
    }
    seg[tid] = lo;
  }
  __syncthreads();
  const int start = seg[0], end = seg[1];
  const int cnt = end - start;

  const int wave = tid >> 6, lane = tid & 63;
  const float4* __restrict__ embv = (const float4*)emb;  // row stride 64

  float a0x = 0.f, a0y = 0.f, a0z = 0.f, a0w = 0.f;
  float a1x = 0.f, a1y = 0.f, a1z = 0.f, a1w = 0.f;
  float a2x = 0.f, a2y = 0.f, a2z = 0.f, a2w = 0.f;
  float a3x = 0.f, a3y = 0.f, a3z = 0.f, a3w = 0.f;

  int r = start + wave;
  for (; r + 12 < end; r += 16) {
    float4 v0 = embv[(size_t)r * 64 + lane];
    float4 v1 = embv[(size_t)(r + 4) * 64 + lane];
    float4 v2 = embv[(size_t)(r + 8) * 64 + lane];
    float4 v3 = embv[(size_t)(r + 12) * 64 + lane];
    a0x += v0.x; a0y += v0.y; a0z += v0.z; a0w += v0.w;
    a1x += v1.x; a1y += v1.y; a1z += v1.z; a1w += v1.w;
    a2x += v2.x; a2y += v2.y; a2z += v2.z; a2w += v2.w;
    a3x += v3.x; a3y += v3.y; a3z += v3.z; a3w += v3.w;
  }
  for (; r < end; r += 4) {
    float4 v = embv[(size_t)r * 64 + lane];
    a0x += v.x; a0y += v.y; a0z += v.z; a0w += v.w;
  }
  a0x += a1x + a2x + a3x;
  a0y += a1y + a2y + a3y;
  a0z += a1z + a2z + a3z;
  a0w += a1w + a2w + a3w;

  __shared__ float4 part[4][64];
  part[wave][lane] = make_float4(a0x, a0y, a0z, a0w);
  __syncthreads();
  if (tid < 64) {
    float4 p0 = part[0][tid], p1 = part[1][tid], p2 = part[2][tid], p3 = part[3][tid];
    const float inv = 1.0f / (float)max(cnt, 1);
    float4 s;
    s.x = (p0.x + p1.x + p2.x + p3.x) * inv;
    s.y = (p0.y + p1.y + p2.y + p3.y) * inv;
    s.z = (p0.z + p1.z + p2.z + p3.z) * inv;
    s.w = (p0.w + p1.w + p2.w + p3.w) * inv;
    ((float4*)gf)[g * 64 + tid] = s;
  }
}

// ---------------------------------------------------------------------------
// Kernel 2: fused MLP cascade, restructured.
// 256 blocks x R=4 graph-rows, 256 threads (one thread per output column j).
// Activations live TRANSPOSED in LDS: xT[k][r] so the per-k read of all 4
// rows is one broadcast ds_read_b128. Thread j streams W[:,j] from L2
// (coalesced across threads) into 4 independent FMA chains.
// ---------------------------------------------------------------------------
#define RR 4

__device__ __forceinline__ float gelu_exact(float v) {
  return 0.5f * v * (1.0f + erff(v * 0.70710678118654752f));
}

// acc[r] = b[j] + sum_k Xt[k][r] * W[k*M+j], optional exact-erf GELU.
template <bool ACT>
__device__ __forceinline__ float4 dense_col(const float* __restrict__ Xt,
                                            const float* __restrict__ W,
                                            const float* __restrict__ b,
                                            int K, int M, int j) {
  float a0 = 0.f, a1 = 0.f, a2 = 0.f, a3 = 0.f;
  const float* __restrict__ wp = W + j;
#pragma unroll 4
  for (int k = 0; k < K; ++k) {
    const float w = wp[k * M];
    const float4 xv = *(const float4*)(Xt + k * 4);
    a0 += xv.x * w;
    a1 += xv.y * w;
    a2 += xv.z * w;
    a3 += xv.w * w;
  }
  const float bj = b[j];
  a0 += bj; a1 += bj; a2 += bj; a3 += bj;
  if (ACT) {
    a0 = gelu_exact(a0); a1 = gelu_exact(a1);
    a2 = gelu_exact(a2); a3 = gelu_exact(a3);
  }
  return make_float4(a0, a1, a2, a3);
}

__global__ __launch_bounds__(256) void mlp_kernel(
    const float* __restrict__ gf,
    const float* __restrict__ pool_w, const float* __restrict__ pool_b,
    const float* __restrict__ w11, const float* __restrict__ b11,
    const float* __restrict__ w12, const float* __restrict__ b12,
    const float* __restrict__ w21, const float* __restrict__ b21,
    const float* __restrict__ w22, const float* __restrict__ b22,
    const float* __restrict__ w31, const float* __restrict__ b31,
    const float* __restrict__ w32, const float* __restrict__ b32,
    float* __restrict__ out) {
  const int rs = blockIdx.x * RR;
  const int tid = threadIdx.x;
  const int j = tid;

  __shared__ float xT[336][4];  // transposed concat input, k up to 333
  __shared__ float hT[128][4];  // transposed hidden
  __shared__ float o[RR][304];  // row-major stage output for softmax

  // load pooled features (transposed store)
  {
    float v[RR];
#pragma unroll
    for (int r = 0; r < RR; ++r) v[r] = gf[(rs + r) * 256 + j];
    *(float4*)&xT[j][0] = make_float4(v[0], v[1], v[2], v[3]);
  }
  __syncthreads();

  // ---- pool: g = gelu(gf @ pool_w + pool_b) ----
  {
    float4 v = dense_col<true>(&xT[0][0], pool_w, pool_b, 256, 256, j);
    __syncthreads();  // all reads of xT done before overwrite
    *(float4*)&xT[j][0] = v;
    out[OFF_G + (rs + 0) * 256 + j] = v.x;
    out[OFF_G + (rs + 1) * 256 + j] = v.y;
    out[OFF_G + (rs + 2) * 256 + j] = v.z;
    out[OFF_G + (rs + 3) * 256 + j] = v.w;
  }
  __syncthreads();

  // ---- ec1 hidden ----
  if (j < 128) {
    float4 v = dense_col<true>(&xT[0][0], w11, b11, 256, 128, j);
    *(float4*)&hT[j][0] = v;
  }
  __syncthreads();
  // ---- ec1 logits ----
  if (j < E1) {
    float4 v = dense_col<false>(&hT[0][0], w12, b12, 128, E1, j);
    o[0][j] = v.x; o[1][j] = v.y; o[2][j] = v.z; o[3][j] = v.w;
    out[OFF_L1 + (rs + 0) * E1 + j] = v.x;
    out[OFF_L1 + (rs + 1) * E1 + j] = v.y;
    out[OFF_L1 + (rs + 2) * E1 + j] = v.z;
    out[OFF_L1 + (rs + 3) * E1 + j] = v.w;
  }
  __syncthreads();
  // softmax rows (thread r handles row r)
  if (tid < RR) {
    float* row = &o[tid][0];
    float m = row[0];
    for (int t = 1; t < E1; ++t) m = fmaxf(m, row[t]);
    float s = 0.f;
    for (int t = 0; t < E1; ++t) { float e = expf(row[t] - m); row[t] = e; s += e; }
    const float inv = 1.0f / s;
    for (int t = 0; t < E1; ++t) row[t] *= inv;
  }
  __syncthreads();
  if (j < E1) {
    float p0 = o[0][j], p1 = o[1][j], p2 = o[2][j], p3 = o[3][j];
    out[OFF_P1 + (rs + 0) * E1 + j] = p0;
    out[OFF_P1 + (rs + 1) * E1 + j] = p1;
    out[OFF_P1 + (rs + 2) * E1 + j] = p2;
    out[OFF_P1 + (rs + 3) * E1 + j] = p3;
    *(float4*)&xT[256 + j][0] = make_float4(p0, p1, p2, p3);
  }
  __syncthreads();

  // ---- ec2 hidden ----
  if (j < 128) {
    float4 v = dense_col<true>(&xT[0][0], w21, b21, 256 + E1, 128, j);
    *(float4*)&hT[j][0] = v;
  }
  __syncthreads();
  // ---- ec2 logits ----
  if (j < E2) {
    float4 v = dense_col<false>(&hT[0][0], w22, b22, 128, E2, j);
    o[0][j] = v.x; o[1][j] = v.y; o[2][j] = v.z; o[3][j] = v.w;
    out[OFF_L2 + (rs + 0) * E2 + j] = v.x;
    out[OFF_L2 + (rs + 1) * E2 + j] = v.y;
    out[OFF_L2 + (rs + 2) * E2 + j] = v.z;
    out[OFF_L2 + (rs + 3) * E2 + j] = v.w;
  }
  __syncthreads();
  if (tid < RR) {
    float* row = &o[tid][0];
    float m = row[0];
    for (int t = 1; t < E2; ++t) m = fmaxf(m, row[t]);
    float s = 0.f;
    for (int t = 0; t < E2; ++t) { float e = expf(row[t] - m); row[t] = e; s += e; }
    const float inv = 1.0f / s;
    for (int t = 0; t < E2; ++t) row[t] *= inv;
  }
  __syncthreads();
  if (j < E2) {
    float p0 = o[0][j], p1 = o[1][j], p2 = o[2][j], p3 = o[3][j];
    *(float4*)&xT[256 + E1 + j][0] = make_float4(p0, p1, p2, p3);
  }
  __syncthreads();

  // ---- ec3 hidden ----
  if (j < 128) {
    float4 v = dense_col<true>(&xT[0][0], w31, b31, 256 + E1 + E2, 128, j);
    *(float4*)&hT[j][0] = v;
  }
  __syncthreads();
  // ---- ec3 logits: straight to global ----
  for (int jj = j; jj < E3; jj += 256) {
    float4 v = dense_col<false>(&hT[0][0], w32, b32, 128, E3, jj);
    out[OFF_L3 + (rs + 0) * E3 + jj] = v.x;
    out[OFF_L3 + (rs + 1) * E3 + jj] = v.y;
    out[OFF_L3 + (rs + 2) * E3 + jj] = v.z;
    out[OFF_L3 + (rs + 3) * E3 + jj] = v.w;
  }
}

// ---------------------------------------------------------------------------
extern "C" void kernel_launch(void* const* d_in, const int* in_sizes, int n_in,
                              void* d_out, int out_size, void* d_ws, size_t ws_size,
                              hipStream_t stream) {
  const float* emb    = (const float*)d_in[0];
  const int*   bidx   = (const int*)d_in[1];
  const float* pool_w = (const float*)d_in[2];
  const float* pool_b = (const float*)d_in[3];
  const float* w11    = (const float*)d_in[4];
  const float* b11    = (const float*)d_in[5];
  const float* w12    = (const float*)d_in[6];
  const float* b12    = (const float*)d_in[7];
  const float* w21    = (const float*)d_in[8];
  const float* b21    = (const float*)d_in[9];
  const float* w22    = (const float*)d_in[10];
  const float* b22    = (const float*)d_in[11];
  const float* w31    = (const float*)d_in[12];
  const float* b31    = (const float*)d_in[13];
  const float* w32    = (const float*)d_in[14];
  const float* b32    = (const float*)d_in[15];
  float* out = (float*)d_out;
  float* gf = (float*)d_ws;  // [1024][256] f32 = 1 MB

  seg_mean_kernel<<<GG, 256, 0, stream>>>(emb, bidx, gf);
  mlp_kernel<<<GG / RR, 256, 0, stream>>>(gf, pool_w, pool_b,
                                          w11, b11, w12, b12,
                                          w21, b21, w22, b22,
                                          w31, b31, w32, b32, out);
}

// Round 3
// 221.864 us; speedup vs baseline: 1.3553x; 1.3553x over previous
//
#include <hip/hip_runtime.h>
#include <hip/hip_bf16.h>
#include <math.h>

// ---------------------------------------------------------------------------
// Problem shapes
// ---------------------------------------------------------------------------
#define NN 400000
#define GG 1024
#define E1 7
#define E2 70
#define E3 300

// Output layout (flat f32)
#define OFF_L1 0
#define OFF_L2 7168
#define OFF_L3 78848
#define OFF_P1 386048
#define OFF_G  393216

// ws layout (float offsets)
#define WS_MEAN 0
#define WS_G    262144
#define WS_P1   524288
#define WS_P2   531456

// ---------------------------------------------------------------------------
// Kernel 1: segment mean — BYTE-IDENTICAL to R0/R1 for attribution.
// ---------------------------------------------------------------------------
__global__ __launch_bounds__(256) void seg_mean_kernel(
    const float* __restrict__ emb, const int* __restrict__ bidx,
    float* __restrict__ gf) {
  const int g = blockIdx.x;
  const int tid = threadIdx.x;
  __shared__ int seg[2];
  if (tid < 2) {
    const int target = g + tid;  // lower_bound(target)
    int lo = 0, hi = NN;
    while (lo < hi) {
      int mid = (lo + hi) >> 1;
      if (bidx[mid] < target) lo = mid + 1; else hi = mid;
    }
    seg[tid] = lo;
  }
  __syncthreads();
  const int start = seg[0], end = seg[1];
  const int cnt = end - start;

  const int wave = tid >> 6, lane = tid & 63;
  const float4* __restrict__ embv = (const float4*)emb;  // row stride 64

  float a0x = 0.f, a0y = 0.f, a0z = 0.f, a0w = 0.f;
  float a1x = 0.f, a1y = 0.f, a1z = 0.f, a1w = 0.f;
  float a2x = 0.f, a2y = 0.f, a2z = 0.f, a2w = 0.f;
  float a3x = 0.f, a3y = 0.f, a3z = 0.f, a3w = 0.f;

  int r = start + wave;
  for (; r + 12 < end; r += 16) {
    float4 v0 = embv[(size_t)r * 64 + lane];
    float4 v1 = embv[(size_t)(r + 4) * 64 + lane];
    float4 v2 = embv[(size_t)(r + 8) * 64 + lane];
    float4 v3 = embv[(size_t)(r + 12) * 64 + lane];
    a0x += v0.x; a0y += v0.y; a0z += v0.z; a0w += v0.w;
    a1x += v1.x; a1y += v1.y; a1z += v1.z; a1w += v1.w;
    a2x += v2.x; a2y += v2.y; a2z += v2.z; a2w += v2.w;
    a3x += v3.x; a3y += v3.y; a3z += v3.z; a3w += v3.w;
  }
  for (; r < end; r += 4) {
    float4 v = embv[(size_t)r * 64 + lane];
    a0x += v.x; a0y += v.y; a0z += v.z; a0w += v.w;
  }
  a0x += a1x + a2x + a3x;
  a0y += a1y + a2y + a3y;
  a0z += a1z + a2z + a3z;
  a0w += a1w + a2w + a3w;

  __shared__ float4 part[4][64];
  part[wave][lane] = make_float4(a0x, a0y, a0z, a0w);
  __syncthreads();
  if (tid < 64) {
    float4 p0 = part[0][tid], p1 = part[1][tid], p2 = part[2][tid], p3 = part[3][tid];
    const float inv = 1.0f / (float)max(cnt, 1);
    float4 s;
    s.x = (p0.x + p1.x + p2.x + p3.x) * inv;
    s.y = (p0.y + p1.y + p2.y + p3.y) * inv;
    s.z = (p0.z + p1.z + p2.z + p3.z) * inv;
    s.w = (p0.w + p1.w + p2.w + p3.w) * inv;
    ((float4*)gf)[g * 64 + tid] = s;
  }
}

// ---------------------------------------------------------------------------
// MLP stage kernels. All: 512 blocks x 256 threads (8 waves/CU -> TLP hides
// L2 latency), LDS-broadcast activations, coalesced weight streams, unroll 8.
// ---------------------------------------------------------------------------
__device__ __forceinline__ float gelu_exact(float v) {
  return 0.5f * v * (1.0f + erff(v * 0.70710678118654752f));
}

// ---- stage 1: g = gelu(mean @ pool_w + pool_b) ----
__global__ __launch_bounds__(256) void pool_kernel(
    const float* __restrict__ gfm, const float* __restrict__ W,
    const float* __restrict__ B, float* __restrict__ gact,
    float* __restrict__ out) {
  const int r0 = blockIdx.x * 2;
  const int j = threadIdx.x;
  __shared__ float xs[2][256];
  xs[0][j] = gfm[r0 * 256 + j];
  xs[1][j] = gfm[(r0 + 1) * 256 + j];
  __syncthreads();
  float a0 = 0.f, a1 = 0.f;
#pragma unroll 8
  for (int k = 0; k < 256; ++k) {
    const float w = W[k * 256 + j];
    a0 += xs[0][k] * w;
    a1 += xs[1][k] * w;
  }
  const float bj = B[j];
  a0 = gelu_exact(a0 + bj);
  a1 = gelu_exact(a1 + bj);
  gact[r0 * 256 + j] = a0;
  gact[(r0 + 1) * 256 + j] = a1;
  out[OFF_G + r0 * 256 + j] = a0;
  out[OFF_G + (r0 + 1) * 256 + j] = a1;
}

// ---- stage 2: ec1 head (hidden K=256 -> logits 7 -> softmax) ----
__global__ __launch_bounds__(256) void ec1_kernel(
    const float* __restrict__ gact,
    const float* __restrict__ W1, const float* __restrict__ B1,
    const float* __restrict__ W2, const float* __restrict__ B2,
    float* __restrict__ out, float* __restrict__ p1) {
  const int r0 = blockIdx.x * 2;
  const int t = threadIdx.x;
  const int r = t >> 7, j = t & 127;
  __shared__ float xs[2][256];
  __shared__ float hs[2][128];
  __shared__ float os[2][E1];
  xs[0][t] = gact[r0 * 256 + t];
  xs[1][t] = gact[(r0 + 1) * 256 + t];
  __syncthreads();
  {
    float a = 0.f;
#pragma unroll 8
    for (int k = 0; k < 256; ++k) a += xs[r][k] * W1[k * 128 + j];
    hs[r][j] = gelu_exact(a + B1[j]);
  }
  __syncthreads();
  if (t < 2 * E1) {
    const int r2 = t / E1, j2 = t - r2 * E1;
    float acc = B2[j2];
#pragma unroll 8
    for (int k = 0; k < 128; ++k) acc += hs[r2][k] * W2[k * E1 + j2];
    os[r2][j2] = acc;
    out[OFF_L1 + (r0 + r2) * E1 + j2] = acc;
  }
  __syncthreads();
  if (t < 2) {
    float m = os[t][0];
    for (int q = 1; q < E1; ++q) m = fmaxf(m, os[t][q]);
    float s = 0.f;
    for (int q = 0; q < E1; ++q) { float e = expf(os[t][q] - m); os[t][q] = e; s += e; }
    const float inv = 1.0f / s;
    for (int q = 0; q < E1; ++q) os[t][q] *= inv;
  }
  __syncthreads();
  if (t < 2 * E1) {
    const int r2 = t / E1, j2 = t - r2 * E1;
    const float v = os[r2][j2];
    out[OFF_P1 + (r0 + r2) * E1 + j2] = v;
    p1[(r0 + r2) * E1 + j2] = v;
  }
}

// ---- stage 3: ec2 head (hidden K=263 -> logits 70 -> softmax) ----
__global__ __launch_bounds__(256) void ec2_kernel(
    const float* __restrict__ gact, const float* __restrict__ p1,
    const float* __restrict__ W1, const float* __restrict__ B1,
    const float* __restrict__ W2, const float* __restrict__ B2,
    float* __restrict__ out, float* __restrict__ p2) {
  const int K1 = 256 + E1;  // 263
  const int r0 = blockIdx.x * 2;
  const int t = threadIdx.x;
  const int r = t >> 7, j = t & 127;
  __shared__ float xs[2][263];
  __shared__ float hs[2][128];
  __shared__ float os[2][E2];
  for (int idx = t; idx < 2 * K1; idx += 256) {
    const int rr = idx / K1, k = idx - rr * K1;
    xs[rr][k] = (k < 256) ? gact[(r0 + rr) * 256 + k]
                          : p1[(r0 + rr) * E1 + (k - 256)];
  }
  __syncthreads();
  {
    float a = 0.f;
#pragma unroll 8
    for (int k = 0; k < K1; ++k) a += xs[r][k] * W1[k * 128 + j];
    hs[r][j] = gelu_exact(a + B1[j]);
  }
  __syncthreads();
  if (t < 2 * E2) {
    const int r2 = t / E2, j2 = t - r2 * E2;
    float acc = B2[j2];
#pragma unroll 8
    for (int k = 0; k < 128; ++k) acc += hs[r2][k] * W2[k * E2 + j2];
    os[r2][j2] = acc;
    out[OFF_L2 + (r0 + r2) * E2 + j2] = acc;
  }
  __syncthreads();
  if (t < 2) {
    float m = os[t][0];
    for (int q = 1; q < E2; ++q) m = fmaxf(m, os[t][q]);
    float s = 0.f;
    for (int q = 0; q < E2; ++q) { float e = expf(os[t][q] - m); os[t][q] = e; s += e; }
    const float inv = 1.0f / s;
    for (int q = 0; q < E2; ++q) os[t][q] *= inv;
  }
  __syncthreads();
  if (t < 2 * E2) {
    const int r2 = t / E2, j2 = t - r2 * E2;
    p2[(r0 + r2) * E2 + j2] = os[r2][j2];
  }
}

// ---- stage 4: ec3 head (hidden K=333 -> logits 300) ----
__global__ __launch_bounds__(256) void ec3_kernel(
    const float* __restrict__ gact, const float* __restrict__ p1,
    const float* __restrict__ p2,
    const float* __restrict__ W1, const float* __restrict__ B1,
    const float* __restrict__ W2, const float* __restrict__ B2,
    float* __restrict__ out) {
  const int K1 = 256 + E1 + E2;  // 333
  const int r0 = blockIdx.x * 2;
  const int t = threadIdx.x;
  const int r = t >> 7, j = t & 127;
  __shared__ float xs[2][333];
  __shared__ float hs[2][128];
  for (int idx = t; idx < 2 * K1; idx += 256) {
    const int rr = idx / K1, k = idx - rr * K1;
    float v;
    if (k < 256)            v = gact[(r0 + rr) * 256 + k];
    else if (k < 256 + E1)  v = p1[(r0 + rr) * E1 + (k - 256)];
    else                    v = p2[(r0 + rr) * E2 + (k - 256 - E1)];
    xs[rr][k] = v;
  }
  __syncthreads();
  {
    float a = 0.f;
#pragma unroll 8
    for (int k = 0; k < K1; ++k) a += xs[r][k] * W1[k * 128 + j];
    hs[r][j] = gelu_exact(a + B1[j]);
  }
  __syncthreads();
  for (int idx = t; idx < 2 * E3; idx += 256) {
    const int r2 = idx / E3, j2 = idx - r2 * E3;
    float acc = B2[j2];
#pragma unroll 8
    for (int k = 0; k < 128; ++k) acc += hs[r2][k] * W2[k * E3 + j2];
    out[OFF_L3 + (r0 + r2) * E3 + j2] = acc;
  }
}

// ---------------------------------------------------------------------------
extern "C" void kernel_launch(void* const* d_in, const int* in_sizes, int n_in,
                              void* d_out, int out_size, void* d_ws, size_t ws_size,
                              hipStream_t stream) {
  const float* emb    = (const float*)d_in[0];
  const int*   bidx   = (const int*)d_in[1];
  const float* pool_w = (const float*)d_in[2];
  const float* pool_b = (const float*)d_in[3];
  const float* w11    = (const float*)d_in[4];
  const float* b11    = (const float*)d_in[5];
  const float* w12    = (const float*)d_in[6];
  const float* b12    = (const float*)d_in[7];
  const float* w21    = (const float*)d_in[8];
  const float* b21    = (const float*)d_in[9];
  const float* w22    = (const float*)d_in[10];
  const float* b22    = (const float*)d_in[11];
  const float* w31    = (const float*)d_in[12];
  const float* b31    = (const float*)d_in[13];
  const float* w32    = (const float*)d_in[14];
  const float* b32    = (const float*)d_in[15];
  float* out = (float*)d_out;
  float* ws  = (float*)d_ws;
  float* gfm  = ws + WS_MEAN;
  float* gact = ws + WS_G;
  float* p1   = ws + WS_P1;
  float* p2   = ws + WS_P2;

  seg_mean_kernel<<<GG, 256, 0, stream>>>(emb, bidx, gfm);
  pool_kernel<<<GG / 2, 256, 0, stream>>>(gfm, pool_w, pool_b, gact, out);
  ec1_kernel<<<GG / 2, 256, 0, stream>>>(gact, w11, b11, w12, b12, out, p1);
  ec2_kernel<<<GG / 2, 256, 0, stream>>>(gact, p1, w21, b21, w22, b22, out, p2);
  ec3_kernel<<<GG / 2, 256, 0, stream>>>(gact, p1, p2, w31, b31, w32, b32, out);
}